// Round 5
// baseline (1746.118 us; speedup 1.0000x reference)
//
#include <hip/hip_runtime.h>
#include <math.h>

#define HWSZ (512*512)

typedef unsigned int u32;
typedef __attribute__((ext_vector_type(8))) short short8;
typedef __attribute__((ext_vector_type(4))) float f32x4;

__device__ __forceinline__ unsigned short f2bf(float f) {
    unsigned u = __float_as_uint(f);
    unsigned r = (u + 0x7FFFu + ((u >> 16) & 1u)) >> 16;
    return (unsigned short)r;
}
__device__ __forceinline__ float bf2f(unsigned short h) {
    return __uint_as_float((unsigned)h << 16);
}

// ---------------------------------------------------------------------------
// Activation format: separate hi/lo bf16 planes, zero-padded [514][516][ch].
// r4 lesson (rocprof): chunking 64-ch pixels by c0-halves reads each 128-B
// line twice across phases (FETCH 34->83 MB); 2-B epilogue stores amplified
// WRITE 33->44 MB. r5: plane-major chunks (hi: passes a*bh + a*bl; lo: a*bh)
// -> every line fetched once per phase; LDS-transpose epilogue -> 16-B stores.
// LDS per chunk: [unit][slot]: unit = (r, cb16[, ghalf]) 1024 B staged by one
// wave-wide global_load_lds dwordx4; slot = (q*16+c16)*16B so fragment
// ds_read_b128 is contiguous/conflict-free (r4 measured 0 conflicts).
// ---------------------------------------------------------------------------
#define PITCH 516
#define PROWS 514
#define LDSPLANE 15360          // head kernel: ushorts per plane (30 units)

__device__ __forceinline__ void dma16(const unsigned short* g, unsigned short* l)
{
    __builtin_amdgcn_global_load_lds(
        (const __attribute__((address_space(1))) unsigned int*)g,
        (__attribute__((address_space(3))) unsigned int*)l,
        16, 0, 0);
}

// ---------------------------------------------------------------------------
// Weight prep: fp32 OIHW -> [tap][co][ci] bf16 hi/lo (Markidis split).
// ---------------------------------------------------------------------------
__global__ void prep_weights(const float* __restrict__ w2, const float* __restrict__ w3,
                             const float* __restrict__ hw1, const float* __restrict__ hw2,
                             const float* __restrict__ hw3,
                             const float* __restrict__ hb1, const float* __restrict__ hb2,
                             const float* __restrict__ hb3,
                             unsigned short* __restrict__ w2h, unsigned short* __restrict__ w2l,
                             unsigned short* __restrict__ w3h, unsigned short* __restrict__ w3l,
                             unsigned short* __restrict__ whh, unsigned short* __restrict__ whl,
                             float* __restrict__ hb16)
{
    int i = blockIdx.x * 256 + threadIdx.x;
    if (i < 18432) {
        int tap = i / 2048, r = i % 2048, co = r / 32, ci = r % 32;
        float v = w2[((co * 32 + ci) * 9) + tap];
        unsigned short h = f2bf(v);
        w2h[i] = h; w2l[i] = f2bf(v - bf2f(h));
    } else if (i < 36864) {
        int e = i - 18432;
        int tap = e / 2048, r = e % 2048, co = r / 64, ci = r % 64;
        float v = w3[((co * 64 + ci) * 9) + tap];
        unsigned short h = f2bf(v);
        w3h[e] = h; w3l[e] = f2bf(v - bf2f(h));
    } else if (i < 41472) {
        int e = i - 36864;
        int tap = e / 512, r = e % 512, co16 = r / 32, ci = r % 32;
        float v = 0.f;
        if (co16 < 12) {
            int hd = co16 >> 2, cl = co16 & 3;
            const float* wp = hd == 0 ? hw1 : (hd == 1 ? hw2 : hw3);
            v = wp[((cl * 32 + ci) * 9) + tap];
        }
        unsigned short h = f2bf(v);
        whh[e] = h; whl[e] = f2bf(v - bf2f(h));
    } else if (i < 41488) {
        int j = i - 41472;
        float v = 0.f;
        if (j < 12) {
            const float* bp = (j >> 2) == 0 ? hb1 : ((j >> 2) == 1 ? hb2 : hb3);
            v = bp[j & 3];
        }
        hb16[j] = v;
    }
}

// ---------------------------------------------------------------------------
// Zero the padded borders of the hi/lo activation planes (once).
// ---------------------------------------------------------------------------
__global__ void zero_border(unsigned short* __restrict__ ph,
                            unsigned short* __restrict__ pl, int logc)
{
    int i = blockIdx.x * 256 + threadIdx.x;
    const int C = 1 << logc;
    if (i >= 3080 * C) return;
    int pix = i >> logc, ch = i & (C - 1);
    int row, col;
    if (pix < 2 * PITCH) {
        row = (pix < PITCH) ? 0 : (PROWS - 1);
        col = (pix < PITCH) ? pix : pix - PITCH;
    } else {
        int q = pix - 2 * PITCH;
        row = 1 + (q >> 2);
        int c = q & 3;
        col = (c == 0) ? 0 : 512 + c;
    }
    size_t o = ((size_t)(row * PITCH + col)) * C + ch;
    ph[o] = 0;
    pl[o] = 0;
}

// ---------------------------------------------------------------------------
// Stage one PLANE (6 rows x 80 cols x CIN ch) into LDS via DMA.
// CIN=64: 60 units (r, cb, ghalf); each unit covers 64 B of 16 pixel-lines;
//         sibling ghalf covers the other 64 B in the SAME phase -> full lines.
// CIN=32: 30 units, each fully contiguous 1024 B.
// ---------------------------------------------------------------------------
template<int CIN>
__device__ __forceinline__ void stage_plane(const unsigned short* __restrict__ src,
                                            unsigned short* s_a,
                                            int w, int lane, int x1, int y0)
{
    const int c16 = lane & 15;
    const int q   = lane >> 4;
    if constexpr (CIN == 64) {
        #pragma unroll
        for (int k = 0; k < 15; ++k) {
            const int u = w * 15 + k;
            const int r = u / 10, rem = u % 10;
            const int cb = rem >> 1, gh = rem & 1;
            const unsigned short* g = src
                + ((size_t)((y0 + r) * PITCH + x1 + cb * 16 + c16)) * 64 + gh * 32 + q * 8;
            dma16(g, s_a + u * 512);
        }
    } else {
        #pragma unroll
        for (int k = 0; k < 8; ++k) {
            const int u = w + 4 * k;
            if (u < 30) {
                const int r = u / 5, cb = u % 5;
                const unsigned short* g = src
                    + ((size_t)((y0 + r) * PITCH + x1 + cb * 16 + c16)) * 32 + q * 8;
                dma16(g, s_a + u * 512);
            }
        }
    }
}

// ---------------------------------------------------------------------------
// One chunk of MFMA work over a staged plane. BOTH=true: a*bh + a*bl (hi
// activations); BOTH=false: a*bh (lo activations).
// ---------------------------------------------------------------------------
template<int CIN, int COUT, bool BOTH>
__device__ __forceinline__ void compute_chunk(const unsigned short* s_a,
    const unsigned short* __restrict__ wh, const unsigned short* __restrict__ wl,
    f32x4 (&acc)[4][COUT/16], int w, int ln, int quad)
{
    constexpr int KS  = CIN / 32;
    constexpr int NTW = COUT / 16;
    #pragma unroll
    for (int tap = 0; tap < 9; ++tap) {
        const int dy = tap / 3, dx = tap % 3;
        #pragma unroll
        for (int ks = 0; ks < KS; ++ks) {
            short8 a[4];
            #pragma unroll
            for (int mt = 0; mt < 4; ++mt) {
                const int mti = w * 4 + mt;
                const int rr  = (mti >> 2) + dy;
                const int col = ((mti & 3) << 4) + ln + dx;
                const int off = (((rr * 5 + (col >> 4)) * KS + ks) << 9)
                              + (((quad << 4) | (col & 15)) << 3);
                a[mt] = *(const short8*)(s_a + off);
            }
            #pragma unroll
            for (int nt = 0; nt < NTW; ++nt) {
                const size_t woff = ((size_t)(tap * COUT + nt * 16 + ln)) * CIN
                                  + ks * 32 + quad * 8;
                short8 bh = *(const short8*)(wh + woff);
                #pragma unroll
                for (int mt = 0; mt < 4; ++mt)
                    acc[mt][nt] = __builtin_amdgcn_mfma_f32_16x16x32_bf16(a[mt], bh, acc[mt][nt], 0, 0, 0);
                if constexpr (BOTH) {
                    short8 bl = *(const short8*)(wl + woff);
                    #pragma unroll
                    for (int mt = 0; mt < 4; ++mt)
                        acc[mt][nt] = __builtin_amdgcn_mfma_f32_16x16x32_bf16(a[mt], bl, acc[mt][nt], 0, 0, 0);
                }
            }
        }
    }
}

// ---------------------------------------------------------------------------
// 3x3 conv + bias + PReLU body. Plane-major chunks; LDS-transpose epilogue
// (scatter acc -> [r][col][co] image -> contiguous 16-B global stores).
// ---------------------------------------------------------------------------
template<int CIN, int COUT>
__device__ __forceinline__ void conv_body(
    const unsigned short* __restrict__ inh, const unsigned short* __restrict__ inl,
    const unsigned short* __restrict__ wh, const unsigned short* __restrict__ wl,
    const float* __restrict__ bias, const float* __restrict__ alpha,
    unsigned short* __restrict__ outh, unsigned short* __restrict__ outl,
    unsigned short* s_a)
{
    constexpr int NTW = COUT / 16;
    const int tid  = threadIdx.x;
    const int w    = tid >> 6;
    const int lane = tid & 63;
    const int ln   = lane & 15;
    const int quad = lane >> 4;
    const int x1   = blockIdx.x * 64;
    const int y0   = blockIdx.y * 4;

    f32x4 acc[4][NTW];
    #pragma unroll
    for (int mt = 0; mt < 4; ++mt)
        #pragma unroll
        for (int nt = 0; nt < NTW; ++nt)
            acc[mt][nt] = (f32x4){0.f, 0.f, 0.f, 0.f};

    // hi-activation chunk: passes a*bh + a*bl
    stage_plane<CIN>(inh, s_a, w, lane, x1, y0);
    asm volatile("s_waitcnt vmcnt(0)" ::: "memory");
    __syncthreads();
    compute_chunk<CIN, COUT, true>(s_a, wh, wl, acc, w, ln, quad);
    __syncthreads();

    // lo-activation chunk: pass a*bh
    stage_plane<CIN>(inl, s_a, w, lane, x1, y0);
    asm volatile("s_waitcnt vmcnt(0)" ::: "memory");
    __syncthreads();
    compute_chunk<CIN, COUT, false>(s_a, wh, wl, acc, w, ln, quad);

    // epilogue: bias + PReLU, LDS transpose, wide coalesced stores
    const float av = alpha[0];
    float bs[NTW];
    #pragma unroll
    for (int nt = 0; nt < NTW; ++nt) bs[nt] = bias[nt * 16 + ln];

    #pragma unroll
    for (int plane = 0; plane < 2; ++plane) {
        __syncthreads();
        #pragma unroll
        for (int mt = 0; mt < 4; ++mt) {
            const int mti = w * 4 + mt;
            const int r   = mti >> 2;
            const int cb  = (mti & 3) << 4;
            #pragma unroll
            for (int nt = 0; nt < NTW; ++nt) {
                #pragma unroll
                for (int reg = 0; reg < 4; ++reg) {
                    float t = acc[mt][nt][reg] + bs[nt];
                    t = t > 0.f ? t : av * t;
                    unsigned short hh = f2bf(t);
                    unsigned short v = plane ? f2bf(t - bf2f(hh)) : hh;
                    s_a[(r * 64 + cb + (quad << 2) + reg) * COUT + nt * 16 + ln] = v;
                }
            }
        }
        __syncthreads();
        unsigned short* op = plane ? outl : outh;
        #pragma unroll
        for (int it = 0; it < COUT / 8; ++it) {
            const int L = (it * 256 + tid) * 8;
            const int r = L / (64 * COUT);
            const int inner = L - r * (64 * COUT);
            const size_t go = ((size_t)((y0 + r + 1) * PITCH + x1 + 1)) * COUT + inner;
            *(uint4*)(op + go) = *(const uint4*)(s_a + L);
        }
    }
}

// conv2 (32->64): staging 30 KB + epilogue 32 KB -> LDS 32768 B; cap VGPR at
// 128 via (256,4) -> 4 blocks/CU.
__global__ __launch_bounds__(256, 4)
void conv_mfma_c2(const unsigned short* __restrict__ inh, const unsigned short* __restrict__ inl,
                  const unsigned short* __restrict__ wh, const unsigned short* __restrict__ wl,
                  const float* __restrict__ bias, const float* __restrict__ alpha,
                  unsigned short* __restrict__ outh, unsigned short* __restrict__ outl)
{
    __shared__ __align__(16) unsigned short s_a[16384];
    conv_body<32, 64>(inh, inl, wh, wl, bias, alpha, outh, outl, s_a);
}

// conv3 (64->32): staging 60 KB -> LDS-capped 2 blocks/CU; regs free (256,2).
__global__ __launch_bounds__(256, 2)
void conv_mfma_c3(const unsigned short* __restrict__ inh, const unsigned short* __restrict__ inl,
                  const unsigned short* __restrict__ wh, const unsigned short* __restrict__ wl,
                  const float* __restrict__ bias, const float* __restrict__ alpha,
                  unsigned short* __restrict__ outh, unsigned short* __restrict__ outl)
{
    __shared__ __align__(16) unsigned short s_a[30720];
    conv_body<64, 32>(inh, inl, wh, wl, bias, alpha, outh, outl, s_a);
}

// ---------------------------------------------------------------------------
// Head conv (32 -> 16 co, 12 valid): unchanged from r4 (CIN=32 staging is
// already full-line; h-writes already float4 via LDS).
// ---------------------------------------------------------------------------
template<int CIN, int RB>
__device__ __forceinline__ void stage_half(const unsigned short* bp, unsigned short* ldsb)
{
    #pragma unroll
    for (int k = 0; k < 15; ++k) {
        const int rid = RB + k;
        const int r = rid / 5, cb = rid % 5;
        dma16(bp + (size_t)(r * PITCH + cb * 16) * CIN, ldsb + rid * 512);
    }
}

template<int CIN>
__device__ __forceinline__ void stage_dma(const unsigned short* __restrict__ inh,
                                          const unsigned short* __restrict__ inl,
                                          unsigned short* s_a,
                                          int w, int lane, int x1, int y0, int c0)
{
    const int c16 = lane & 15;
    const int g   = lane >> 4;
    const unsigned short* base = (w < 2) ? inh : inl;
    unsigned short* ldsb = s_a + ((w < 2) ? 0 : LDSPLANE);
    const unsigned short* bp = base
        + ((size_t)(y0 * PITCH + x1 + c16)) * CIN + c0 + g * 8;
    if (w & 1) stage_half<CIN, 15>(bp, ldsb);
    else       stage_half<CIN, 0>(bp, ldsb);
}

__device__ __forceinline__ int frag_off(int rr, int col, int quad)
{
    return ((rr * 5 + (col >> 4)) << 9) + (((quad << 4) | (col & 15)) << 3);
}

__global__ __launch_bounds__(256, 2)
void head_mfma(const unsigned short* __restrict__ inh, const unsigned short* __restrict__ inl,
               const unsigned short* __restrict__ wh, const unsigned short* __restrict__ wl,
               const float* __restrict__ hb,
               float* __restrict__ h, float* __restrict__ g2, int b)
{
    __shared__ __align__(16) unsigned short s_a[2 * LDSPLANE];
    __shared__ float s_red[4][16];

    const int tid  = threadIdx.x;
    const int w    = tid >> 6;
    const int lane = tid & 63;
    const int ln   = lane & 15;
    const int quad = lane >> 4;
    const int x1   = blockIdx.x * 64;
    const int y0   = blockIdx.y * 4;

    f32x4 acc[4];
    #pragma unroll
    for (int mt = 0; mt < 4; ++mt) acc[mt] = (f32x4){0.f, 0.f, 0.f, 0.f};

    stage_dma<32>(inh, inl, s_a, w, lane, x1, y0, 0);
    asm volatile("s_waitcnt vmcnt(0)" ::: "memory");
    __syncthreads();

    #pragma unroll
    for (int tap = 0; tap < 9; ++tap) {
        const int dy = tap / 3, dx = tap % 3;
        size_t boff = (size_t)tap * 512 + ln * 32 + quad * 8;
        short8 bh = *(const short8*)(wh + boff);
        short8 bl = *(const short8*)(wl + boff);
        short8 ah[4], al[4];
        #pragma unroll
        for (int mt = 0; mt < 4; ++mt) {
            const int mti = w * 4 + mt;
            const int rr  = (mti >> 2) + dy;
            const int col = ((mti & 3) << 4) + ln + dx;
            const int off = frag_off(rr, col, quad);
            ah[mt] = *(const short8*)(s_a + off);
            al[mt] = *(const short8*)(s_a + LDSPLANE + off);
        }
        #pragma unroll
        for (int mt = 0; mt < 4; ++mt)
            acc[mt] = __builtin_amdgcn_mfma_f32_16x16x32_bf16(ah[mt], bh, acc[mt], 0, 0, 0);
        #pragma unroll
        for (int mt = 0; mt < 4; ++mt)
            acc[mt] = __builtin_amdgcn_mfma_f32_16x16x32_bf16(al[mt], bh, acc[mt], 0, 0, 0);
        #pragma unroll
        for (int mt = 0; mt < 4; ++mt)
            acc[mt] = __builtin_amdgcn_mfma_f32_16x16x32_bf16(ah[mt], bl, acc[mt], 0, 0, 0);
    }

    __syncthreads();                       // s_a reads done; reuse as s_h
    float* s_h = (float*)s_a;              // [12][260]
    const float bs = hb[ln];
    float psum = 0.f;
    #pragma unroll
    for (int mt = 0; mt < 4; ++mt) {
        const int mti  = w * 4 + mt;
        const int base = (mti >> 2) * 64 + ((mti & 3) << 4) + quad * 4;
        #pragma unroll
        for (int reg = 0; reg < 4; ++reg) {
            float v = acc[mt][reg] + bs;
            if (ln < 12) s_h[ln * 260 + base + reg] = v;
            psum += v;                     // lanes >= 12: weights+bias zero -> 0
        }
    }
    psum += __shfl_down(psum, 16);
    psum += __shfl_down(psum, 32);
    if (lane < 16) s_red[w][lane] = psum;
    __syncthreads();

    if (tid < 192) {
        const int co = tid >> 4, ch = tid & 15;
        const float* src = s_h + co * 260 + ch * 16;
        float4 v0 = *(const float4*)(src);
        float4 v1 = *(const float4*)(src + 4);
        float4 v2 = *(const float4*)(src + 8);
        float4 v3 = *(const float4*)(src + 12);
        const int hd = co >> 2, cl = co & 3;
        float* dst = h + ((size_t)((hd * 8 + b) * 4 + cl)) * HWSZ
                       + (size_t)(y0 + (ch >> 2)) * 512 + x1 + ((ch & 3) << 4);
        *(float4*)(dst)      = v0;
        *(float4*)(dst + 4)  = v1;
        *(float4*)(dst + 8)  = v2;
        *(float4*)(dst + 12) = v3;
    }
    if (tid < 12) {
        float t = s_red[0][tid] + s_red[1][tid] + s_red[2][tid] + s_red[3][tid];
        atomicAdd(&g2[(tid >> 2) * 32 + b * 4 + (tid & 3)], t);
    }
}

// ---------------------------------------------------------------------------
// conv1: 3 -> 32, fp32 direct, thread-per-pixel, writes padded dual planes.
// ---------------------------------------------------------------------------
__global__ __launch_bounds__(256)
void conv1_nhwc(const float* __restrict__ x, const float* __restrict__ wgt,
                const float* __restrict__ bias, const float* __restrict__ alpha,
                unsigned short* __restrict__ outh, unsigned short* __restrict__ outl)
{
    __shared__ float s_in[3][6][72];
    __shared__ float s_w[3][9][32];
    __shared__ float s_b[32];
    const int tid = threadIdx.x;
    const int x1 = blockIdx.x * 64, y0 = blockIdx.y * 4;

    for (int i = tid; i < 3 * 6 * 66; i += 256) {
        int ci = i / 396, rm = i % 396;
        int r = rm / 66, cc = rm % 66;
        int gy = y0 - 1 + r, gx = x1 - 1 + cc;
        float v = 0.f;
        if ((unsigned)gy < 512u && (unsigned)gx < 512u)
            v = x[(size_t)ci * HWSZ + gy * 512 + gx];
        s_in[ci][r][cc] = v;
    }
    for (int i = tid; i < 864; i += 256) {
        int co = i & 31, rm = i >> 5;
        int ci = rm / 9, tap = rm % 9;
        s_w[ci][tap][co] = wgt[(co * 3 + ci) * 9 + tap];
    }
    if (tid < 32) s_b[tid] = bias[tid];
    __syncthreads();

    const int ty = tid >> 6, tx = tid & 63;
    float acc[32];
    #pragma unroll
    for (int i = 0; i < 32; ++i) acc[i] = 0.f;
    #pragma unroll
    for (int ci = 0; ci < 3; ++ci)
        #pragma unroll
        for (int tap = 0; tap < 9; ++tap) {
            const int dy = tap / 3, dx = tap % 3;
            float iv = s_in[ci][ty + dy][tx + dx];
            #pragma unroll
            for (int c4 = 0; c4 < 8; ++c4) {
                float4 wv = *(const float4*)&s_w[ci][tap][c4 * 4];
                acc[c4*4+0] = fmaf(iv, wv.x, acc[c4*4+0]);
                acc[c4*4+1] = fmaf(iv, wv.y, acc[c4*4+1]);
                acc[c4*4+2] = fmaf(iv, wv.z, acc[c4*4+2]);
                acc[c4*4+3] = fmaf(iv, wv.w, acc[c4*4+3]);
            }
        }
    const float av = alpha[0];
    u32 ph[16], pl[16];
    #pragma unroll
    for (int cp = 0; cp < 16; ++cp) {
        float t0 = acc[2*cp]     + s_b[2*cp];     t0 = t0 > 0.f ? t0 : av * t0;
        float t1 = acc[2*cp + 1] + s_b[2*cp + 1]; t1 = t1 > 0.f ? t1 : av * t1;
        unsigned short h0 = f2bf(t0), h1 = f2bf(t1);
        unsigned short l0 = f2bf(t0 - bf2f(h0)), l1 = f2bf(t1 - bf2f(h1));
        ph[cp] = (u32)h0 | ((u32)h1 << 16);
        pl[cp] = (u32)l0 | ((u32)l1 << 16);
    }
    size_t o = ((size_t)((y0 + ty + 1) * PITCH + x1 + tx + 1)) * 32;
    #pragma unroll
    for (int q = 0; q < 4; ++q) {
        *(uint4*)(outh + o + q * 8) = (uint4){ph[4*q], ph[4*q+1], ph[4*q+2], ph[4*q+3]};
        *(uint4*)(outl + o + q * 8) = (uint4){pl[4*q], pl[4*q+1], pl[4*q+2], pl[4*q+3]};
    }
}

// ---------------------------------------------------------------------------
__global__ void zero_k(float* p, int n)
{
    int i = blockIdx.x * 256 + threadIdx.x;
    if (i < n) p[i] = 0.f;
}

__global__ void ca_kernel(const float* __restrict__ g,
                          const float* __restrict__ c11, const float* __restrict__ c12,
                          const float* __restrict__ c21, const float* __restrict__ c22,
                          const float* __restrict__ c31, const float* __restrict__ c32,
                          float* __restrict__ sOut)
{
    int t = threadIdx.x;
    if (t >= 24) return;
    int head = t / 8, b = t % 8;
    const float* c1 = head == 0 ? c11 : (head == 1 ? c21 : c31);
    const float* c2 = head == 0 ? c12 : (head == 1 ? c22 : c32);
    float m[4], v[4];
    #pragma unroll
    for (int i = 0; i < 4; ++i) m[i] = g[head * 32 + b * 4 + i] * (1.0f / 262144.0f);
    #pragma unroll
    for (int j = 0; j < 4; ++j) {
        float xv = c1[j*4+0]*m[0] + c1[j*4+1]*m[1] + c1[j*4+2]*m[2] + c1[j*4+3]*m[3];
        v[j] = fmaxf(xv, 0.f);
    }
    #pragma unroll
    for (int j = 0; j < 4; ++j) {
        float xv = c2[j*4+0]*v[0] + c2[j*4+1]*v[1] + c2[j*4+2]*v[2] + c2[j*4+3]*v[3];
        sOut[head * 32 + b * 4 + j] = 1.f / (1.f + __expf(-xv));
    }
}

// ---------------------------------------------------------------------------
// Integral image (SAT): 513x513 per (b,c) plane.
// ---------------------------------------------------------------------------
__global__ __launch_bounds__(256)
void sat_row(const float* __restrict__ src, float* __restrict__ S)
{
    const int y  = blockIdx.x;
    const int bc = blockIdx.y;
    float* Sp = S + (size_t)bc * 263169;
    const int tid = threadIdx.x;
    if (y == 0) {
        for (int i = tid; i < 513; i += 256) Sp[i] = 0.f;
        return;
    }
    const float2* row2 = (const float2*)(src + (size_t)bc * HWSZ + (size_t)(y - 1) * 512);
    float2 ab = row2[tid];
    float ps = ab.x + ab.y;
    float v = ps;
    const int lane = tid & 63;
    #pragma unroll
    for (int off = 1; off < 64; off <<= 1) {
        float u = __shfl_up(v, off);
        if (lane >= off) v += u;
    }
    __shared__ float wsum[4];
    const int wv = tid >> 6;
    if (lane == 63) wsum[wv] = v;
    __syncthreads();
    float woff = 0.f;
    #pragma unroll
    for (int k = 0; k < 4; ++k) if (k < wv) woff += wsum[k];
    float excl = woff + v - ps;
    float* o = Sp + (size_t)y * 513;
    if (tid == 0) o[0] = 0.f;
    o[1 + 2 * tid] = excl + ab.x;
    o[2 + 2 * tid] = excl + ab.x + ab.y;
}

__global__ __launch_bounds__(256)
void sat_col(float* __restrict__ S)
{
    const int bc = blockIdx.x;
    const int c  = 1 + blockIdx.y * 256 + threadIdx.x;   // 1..512
    float* P = S + (size_t)bc * 263169 + c;
    float run = 0.f;
    for (int r0 = 1; r0 <= 512; r0 += 16) {
        float v[16];
        #pragma unroll
        for (int i = 0; i < 16; ++i) v[i] = P[(size_t)(r0 + i) * 513];
        #pragma unroll
        for (int i = 0; i < 16; ++i) { run += v[i]; v[i] = run; }
        #pragma unroll
        for (int i = 0; i < 16; ++i) P[(size_t)(r0 + i) * 513] = v[i];
    }
}

__device__ __forceinline__ float boxsum(const float* __restrict__ S, int y, int x, int p)
{
    int y0 = max(y - p, 0), x0 = max(x - p, 0);
    int y1 = min(y + p, 511) + 1, x1 = min(x + p, 511) + 1;
    return S[y1 * 513 + x1] - S[y0 * 513 + x1] - S[y1 * 513 + x0] + S[y0 * 513 + x0];
}

__global__ __launch_bounds__(256)
void fuse_kernel(const float* __restrict__ cur, const float* __restrict__ h,
                 const float* __restrict__ sv, const float* __restrict__ S,
                 float* __restrict__ out, int head)
{
    const int idx = blockIdx.x * 256 + threadIdx.x;
    const int b   = idx >> 18;
    const int rem = idx & 262143;
    const int y   = rem >> 9;
    const int x   = rem & 511;

    const float* sp = sv + head * 32 + b * 4;
    const float* hp = h + (size_t)((head * 8 + b) * 4) * HWSZ + rem;
    float z0 = hp[0]          * sp[0];
    float z1 = hp[HWSZ]       * sp[1];
    float z2 = hp[2 * HWSZ]   * sp[2];
    float z3 = hp[3 * HWSZ]   * sp[3];
    float m  = fmaxf(fmaxf(z0, z1), fmaxf(z2, z3));
    float e0 = __expf(z0 - m), e1 = __expf(z1 - m), e2 = __expf(z2 - m), e3 = __expf(z3 - m);
    float inv = 1.f / (e0 + e1 + e2 + e3);
    float p0 = e0 * inv, p1 = e1 * inv, p2 = e2 * inv, p3 = e3 * inv;

    #pragma unroll
    for (int c = 0; c < 3; ++c) {
        const float* Sp = S + (size_t)(b * 3 + c) * 263169;
        float xv = cur[((size_t)b * 3 + c) * HWSZ + rem];
        float m2 = boxsum(Sp, y, x, 2)  * (1.f / 25.f);
        float m3 = boxsum(Sp, y, x, 7)  * (1.f / 225.f);
        float m4 = boxsum(Sp, y, x, 12) * (1.f / 625.f);
        out[((size_t)b * 3 + c) * HWSZ + rem] = p0 * xv + p1 * m2 + p2 * m3 + p3 * m4;
    }
}

// ---------------------------------------------------------------------------
// Workspace: t1h/t1l 8,487,168 ush each | t2h/t2l 16,974,336 ush each
// | hbuf 25,165,824 fl | gbuf/sbuf 96 fl | weights 82,944 ush | hb16 16 fl
// ---------------------------------------------------------------------------
extern "C" void kernel_launch(void* const* d_in, const int* in_sizes, int n_in,
                              void* d_out, int out_size, void* d_ws, size_t ws_size,
                              hipStream_t stream)
{
    (void)in_sizes; (void)n_in; (void)out_size; (void)ws_size;
    const float* x    = (const float*)d_in[0];
    const float* bw1  = (const float*)d_in[1];
    const float* bb1  = (const float*)d_in[2];
    const float* a1   = (const float*)d_in[3];
    const float* bw2  = (const float*)d_in[4];
    const float* bb2  = (const float*)d_in[5];
    const float* a2   = (const float*)d_in[6];
    const float* bw3  = (const float*)d_in[7];
    const float* bb3  = (const float*)d_in[8];
    const float* a3   = (const float*)d_in[9];
    const float* h1w  = (const float*)d_in[10];
    const float* h1b  = (const float*)d_in[11];
    const float* h1c1 = (const float*)d_in[12];
    const float* h1c2 = (const float*)d_in[13];
    const float* h2w  = (const float*)d_in[14];
    const float* h2b  = (const float*)d_in[15];
    const float* h2c1 = (const float*)d_in[16];
    const float* h2c2 = (const float*)d_in[17];
    const float* h3w  = (const float*)d_in[18];
    const float* h3b  = (const float*)d_in[19];
    const float* h3c1 = (const float*)d_in[20];
    const float* h3c2 = (const float*)d_in[21];

    const size_t T1P = (size_t)PROWS * PITCH * 32;   //  8,487,168
    const size_t T2P = (size_t)PROWS * PITCH * 64;   // 16,974,336

    unsigned short* t1h = (unsigned short*)d_ws;
    unsigned short* t1l = t1h + T1P;
    unsigned short* t2h = t1l + T1P;
    unsigned short* t2l = t2h + T2P;
    float* hbuf = (float*)(t2l + T2P);               // 25,165,824 fl
    float* gbuf = hbuf + 25165824;                   // 96
    float* sbuf = gbuf + 96;                         // 96
    unsigned short* wb = (unsigned short*)(sbuf + 96);
    unsigned short* w2h = wb;                        // 18432
    unsigned short* w2l = wb + 18432;
    unsigned short* w3h = wb + 36864;
    unsigned short* w3l = wb + 55296;
    unsigned short* whh = wb + 73728;                // 4608
    unsigned short* whl = wb + 78336;
    float* hb16 = (float*)(wb + 82944);              // 16
    float* SAT  = (float*)t2h;                       // alias (after batch loop)
    float* ping = (float*)t1h;                       // alias (after batch loop)

    dim3 blk(256);

    prep_weights<<<dim3(163), blk, 0, stream>>>(bw2, bw3, h1w, h2w, h3w,
                                                h1b, h2b, h3b,
                                                w2h, w2l, w3h, w3l, whh, whl, hb16);
    zero_k<<<dim3(1), dim3(128), 0, stream>>>(gbuf, 96);
    zero_border<<<dim3(385), blk, 0, stream>>>(t1h, t1l, 5);
    zero_border<<<dim3(770), blk, 0, stream>>>(t2h, t2l, 6);

    // per-batch body: x[b] -> t1 -> t2 -> t1 -> heads
    for (int b = 0; b < 8; ++b) {
        conv1_nhwc<<<dim3(8, 128), blk, 0, stream>>>(x + (size_t)b * 3 * HWSZ,
                                                     bw1, bb1, a1, t1h, t1l);
        conv_mfma_c2<<<dim3(8, 128), blk, 0, stream>>>(t1h, t1l, w2h, w2l, bb2, a2, t2h, t2l);
        conv_mfma_c3<<<dim3(8, 128), blk, 0, stream>>>(t2h, t2l, w3h, w3l, bb3, a3, t1h, t1l);
        head_mfma<<<dim3(8, 128), blk, 0, stream>>>(t1h, t1l, whh, whl, hb16, hbuf, gbuf, b);
    }

    ca_kernel<<<dim3(1), dim3(64), 0, stream>>>(gbuf, h1c1, h1c2, h2c1, h2c2,
                                                h3c1, h3c2, sbuf);

    // fuse chain: x -> ping -> ping(in place) -> d_out
    const float* cur = x;
    for (int i = 0; i < 3; ++i) {
        sat_row<<<dim3(513, 24), blk, 0, stream>>>(cur, SAT);
        sat_col<<<dim3(24, 2), blk, 0, stream>>>(SAT);
        float* nxt = (i == 2) ? (float*)d_out : ping;
        fuse_kernel<<<dim3(8192), blk, 0, stream>>>(cur, hbuf, sbuf, SAT, nxt, i);
        cur = nxt;
    }
}

// Round 6
// 1449.356 us; speedup vs baseline: 1.2048x; 1.2048x over previous
//
#include <hip/hip_runtime.h>
#include <math.h>

#define HWSZ (512*512)

typedef unsigned int u32;
typedef __attribute__((ext_vector_type(8))) short short8;
typedef __attribute__((ext_vector_type(4))) float f32x4;
typedef __attribute__((ext_vector_type(4))) float f4;
typedef __attribute__((ext_vector_type(4), aligned(4))) float f4u;   // 4-B-aligned vector load

__device__ __forceinline__ unsigned short f2bf(float f) {
    unsigned u = __float_as_uint(f);
    unsigned r = (u + 0x7FFFu + ((u >> 16) & 1u)) >> 16;
    return (unsigned short)r;
}
__device__ __forceinline__ float bf2f(unsigned short h) {
    return __uint_as_float((unsigned)h << 16);
}
__device__ __forceinline__ u32 packhl(float v) {
    unsigned short h = f2bf(v);
    unsigned short l = f2bf(v - bf2f(h));
    return (u32)h | ((u32)l << 16);
}

// LDS tile geometry for MFMA convs: 6 rows x 72 cols x 32 ci, hi/lo planes.
// granule (8 ci) stride GRAN=3464 shorts (6928 B == 4 banks mod 32): even bank
// spread for both staging b128 writes and fragment b128 reads.
// NOTE (r1-r5 history): every deviation from this exact geometry/codegen
// (68-col tile, launch-bounds>=3, reg-staged ILP, global_load_lds dual-plane
// format) regressed 7-23%; the allocator pins VGPR=68/64 and serializes
// staging, or the format doubles HBM traffic. This file restores the r0
// conv pipeline verbatim (VGPR 88, 61.9us convs) and optimizes fuse instead.
#define GRAN  3464
#define APLANE (4 * GRAN)   // 13856 shorts per plane

// ---------------------------------------------------------------------------
// Weight prep: fp32 OIHW -> [tap][co][ci] bf16 hi/lo (Markidis split).
// conv2 (64x32), conv3 (32x64), heads packed+padded to 16 co (12 valid).
// ---------------------------------------------------------------------------
__global__ void prep_weights(const float* __restrict__ w2, const float* __restrict__ w3,
                             const float* __restrict__ hw1, const float* __restrict__ hw2,
                             const float* __restrict__ hw3,
                             const float* __restrict__ hb1, const float* __restrict__ hb2,
                             const float* __restrict__ hb3,
                             unsigned short* __restrict__ w2h, unsigned short* __restrict__ w2l,
                             unsigned short* __restrict__ w3h, unsigned short* __restrict__ w3l,
                             unsigned short* __restrict__ whh, unsigned short* __restrict__ whl,
                             float* __restrict__ hb16)
{
    int i = blockIdx.x * 256 + threadIdx.x;
    if (i < 18432) {
        int tap = i / 2048, r = i % 2048, co = r / 32, ci = r % 32;
        float v = w2[((co * 32 + ci) * 9) + tap];
        unsigned short h = f2bf(v);
        w2h[i] = h; w2l[i] = f2bf(v - bf2f(h));
    } else if (i < 36864) {
        int e = i - 18432;
        int tap = e / 2048, r = e % 2048, co = r / 64, ci = r % 64;
        float v = w3[((co * 64 + ci) * 9) + tap];
        unsigned short h = f2bf(v);
        w3h[e] = h; w3l[e] = f2bf(v - bf2f(h));
    } else if (i < 41472) {
        int e = i - 36864;
        int tap = e / 512, r = e % 512, co16 = r / 32, ci = r % 32;
        float v = 0.f;
        if (co16 < 12) {
            int hd = co16 >> 2, cl = co16 & 3;
            const float* wp = hd == 0 ? hw1 : (hd == 1 ? hw2 : hw3);
            v = wp[((cl * 32 + ci) * 9) + tap];
        }
        unsigned short h = f2bf(v);
        whh[e] = h; whl[e] = f2bf(v - bf2f(h));
    } else if (i < 41488) {
        int j = i - 41472;
        float v = 0.f;
        if (j < 12) {
            const float* bp = (j >> 2) == 0 ? hb1 : ((j >> 2) == 1 ? hb2 : hb3);
            v = bp[j & 3];
        }
        hb16[j] = v;
    }
}

// ---------------------------------------------------------------------------
// Stage 6x72(66 used)xCIN-chunk tile from packed hi/lo NHWC global into LDS.
// Wave lanes: 16 cols x 4 ci-granules -> 2 KB contiguous global per instr.
// ---------------------------------------------------------------------------
template<int CIN>
__device__ __forceinline__ void stage_tile(const u32* __restrict__ in,
                                           unsigned short* s_a,
                                           int w, int lane, int x1, int y0, int c0)
{
    const int c16 = lane & 15;
    const int g   = lane >> 4;
    for (int it = w; it < 30; it += 4) {
        int r  = it / 5;
        int cb = it % 5;
        int col = cb * 16 + c16;
        if (col < 66) {
            int gy = y0 - 1 + r;
            int gx = x1 - 1 + col;
            u32 d0=0,d1=0,d2=0,d3=0,d4=0,d5=0,d6=0,d7=0;
            if ((unsigned)gy < 512u && (unsigned)gx < 512u) {
                const uint4* p = (const uint4*)(in + ((size_t)(gy * 512 + gx)) * CIN + c0 + g * 8);
                uint4 A = p[0], B = p[1];
                d0=A.x; d1=A.y; d2=A.z; d3=A.w; d4=B.x; d5=B.y; d6=B.z; d7=B.w;
            }
            uint4 hi, lo;
            hi.x = (d0 & 0xffffu) | (d1 << 16);
            hi.y = (d2 & 0xffffu) | (d3 << 16);
            hi.z = (d4 & 0xffffu) | (d5 << 16);
            hi.w = (d6 & 0xffffu) | (d7 << 16);
            lo.x = (d0 >> 16) | (d1 & 0xffff0000u);
            lo.y = (d2 >> 16) | (d3 & 0xffff0000u);
            lo.z = (d4 >> 16) | (d5 & 0xffff0000u);
            lo.w = (d6 >> 16) | (d7 & 0xffff0000u);
            int e = (r * 72 + col) * 8;
            *(uint4*)(s_a + g * GRAN + e) = hi;
            *(uint4*)(s_a + APLANE + g * GRAN + e) = lo;
        }
    }
}

// ---------------------------------------------------------------------------
// 3x3 conv + bias + PReLU, NHWC hi/lo packed in/out, bf16 MFMA 3-pass.
// Tile: 4 rows x 64 cols x COUT. 4 waves x 4 m-tiles; NTW n-tiles per wave.
// ---------------------------------------------------------------------------
template<int CIN, int COUT>
__global__ __launch_bounds__(256, 2)
void conv_mfma(const u32* __restrict__ in,
               const unsigned short* __restrict__ wh,
               const unsigned short* __restrict__ wl,
               const float* __restrict__ bias,
               const float* __restrict__ alpha,
               u32* __restrict__ out)
{
    constexpr int NTW = COUT / 16;
    __shared__ __align__(16) unsigned short s_a[2 * APLANE];

    const int tid  = threadIdx.x;
    const int w    = tid >> 6;
    const int lane = tid & 63;
    const int ln   = lane & 15;
    const int quad = lane >> 4;
    const int x1   = blockIdx.x * 64;
    const int y0   = blockIdx.y * 4;

    f32x4 acc[4][NTW];
    #pragma unroll
    for (int mt = 0; mt < 4; ++mt)
        #pragma unroll
        for (int nt = 0; nt < NTW; ++nt)
            acc[mt][nt] = (f32x4){0.f, 0.f, 0.f, 0.f};

    for (int c0 = 0; c0 < CIN; c0 += 32) {
        if (c0) __syncthreads();
        stage_tile<CIN>(in, s_a, w, lane, x1, y0, c0);
        __syncthreads();

        #pragma unroll
        for (int tap = 0; tap < 9; ++tap) {
            const int dy = tap / 3, dx = tap % 3;
            short8 bh[NTW], bl[NTW];
            #pragma unroll
            for (int nt = 0; nt < NTW; ++nt) {
                size_t off = ((size_t)(tap * COUT + nt * 16 + ln)) * CIN + c0 + quad * 8;
                bh[nt] = *(const short8*)(wh + off);
                bl[nt] = *(const short8*)(wl + off);
            }
            short8 ah[4], al[4];
            #pragma unroll
            for (int mt = 0; mt < 4; ++mt) {
                const int mti = w * 4 + mt;
                const int rr  = (mti >> 2) + dy;
                const int col = ((mti & 3) << 4) + ln + dx;
                const int off = quad * GRAN + (rr * 72 + col) * 8;
                ah[mt] = *(const short8*)(s_a + off);
                al[mt] = *(const short8*)(s_a + APLANE + off);
            }
            #pragma unroll
            for (int mt = 0; mt < 4; ++mt)
                #pragma unroll
                for (int nt = 0; nt < NTW; ++nt)
                    acc[mt][nt] = __builtin_amdgcn_mfma_f32_16x16x32_bf16(ah[mt], bh[nt], acc[mt][nt], 0, 0, 0);
            #pragma unroll
            for (int mt = 0; mt < 4; ++mt)
                #pragma unroll
                for (int nt = 0; nt < NTW; ++nt)
                    acc[mt][nt] = __builtin_amdgcn_mfma_f32_16x16x32_bf16(al[mt], bh[nt], acc[mt][nt], 0, 0, 0);
            #pragma unroll
            for (int mt = 0; mt < 4; ++mt)
                #pragma unroll
                for (int nt = 0; nt < NTW; ++nt)
                    acc[mt][nt] = __builtin_amdgcn_mfma_f32_16x16x32_bf16(ah[mt], bl[nt], acc[mt][nt], 0, 0, 0);
        }
    }

    const float av = alpha[0];
    float bs[NTW];
    #pragma unroll
    for (int nt = 0; nt < NTW; ++nt) bs[nt] = bias[nt * 16 + ln];
    #pragma unroll
    for (int mt = 0; mt < 4; ++mt) {
        const int mti = w * 4 + mt;
        const int y   = y0 + (mti >> 2);
        const int xb  = x1 + ((mti & 3) << 4) + quad * 4;
        #pragma unroll
        for (int nt = 0; nt < NTW; ++nt) {
            const int co = nt * 16 + ln;
            #pragma unroll
            for (int reg = 0; reg < 4; ++reg) {
                float t = acc[mt][nt][reg] + bs[nt];
                t = t > 0.f ? t : av * t;
                out[((size_t)(y * 512 + xb + reg)) * COUT + co] = packhl(t);
            }
        }
    }
}

// ---------------------------------------------------------------------------
// Head conv: 32 -> 16 co (12 valid = 3 heads x 4), MFMA 3-pass, + GAP atomics.
// Writes h planes NCHW fp32 via LDS transpose (coalesced 64-B segments).
// ---------------------------------------------------------------------------
__global__ __launch_bounds__(256, 2)
void head_mfma(const u32* __restrict__ in,
               const unsigned short* __restrict__ wh,
               const unsigned short* __restrict__ wl,
               const float* __restrict__ hb,
               float* __restrict__ h, float* __restrict__ g2, int b)
{
    __shared__ __align__(16) unsigned short s_a[2 * APLANE];
    __shared__ float s_red[4][16];

    const int tid  = threadIdx.x;
    const int w    = tid >> 6;
    const int lane = tid & 63;
    const int ln   = lane & 15;
    const int quad = lane >> 4;
    const int x1   = blockIdx.x * 64;
    const int y0   = blockIdx.y * 4;

    f32x4 acc[4];
    #pragma unroll
    for (int mt = 0; mt < 4; ++mt) acc[mt] = (f32x4){0.f, 0.f, 0.f, 0.f};

    stage_tile<32>(in, s_a, w, lane, x1, y0, 0);
    __syncthreads();

    #pragma unroll
    for (int tap = 0; tap < 9; ++tap) {
        const int dy = tap / 3, dx = tap % 3;
        size_t boff = (size_t)tap * 512 + ln * 32 + quad * 8;
        short8 bh = *(const short8*)(wh + boff);
        short8 bl = *(const short8*)(wl + boff);
        short8 ah[4], al[4];
        #pragma unroll
        for (int mt = 0; mt < 4; ++mt) {
            const int mti = w * 4 + mt;
            const int rr  = (mti >> 2) + dy;
            const int col = ((mti & 3) << 4) + ln + dx;
            const int off = quad * GRAN + (rr * 72 + col) * 8;
            ah[mt] = *(const short8*)(s_a + off);
            al[mt] = *(const short8*)(s_a + APLANE + off);
        }
        #pragma unroll
        for (int mt = 0; mt < 4; ++mt)
            acc[mt] = __builtin_amdgcn_mfma_f32_16x16x32_bf16(ah[mt], bh, acc[mt], 0, 0, 0);
        #pragma unroll
        for (int mt = 0; mt < 4; ++mt)
            acc[mt] = __builtin_amdgcn_mfma_f32_16x16x32_bf16(al[mt], bh, acc[mt], 0, 0, 0);
        #pragma unroll
        for (int mt = 0; mt < 4; ++mt)
            acc[mt] = __builtin_amdgcn_mfma_f32_16x16x32_bf16(ah[mt], bl, acc[mt], 0, 0, 0);
    }

    __syncthreads();                       // s_a reads done; reuse as s_h
    float* s_h = (float*)s_a;              // [12][260]
    const float bs = hb[ln];
    float psum = 0.f;
    #pragma unroll
    for (int mt = 0; mt < 4; ++mt) {
        const int mti  = w * 4 + mt;
        const int base = (mti >> 2) * 64 + ((mti & 3) << 4) + quad * 4;
        #pragma unroll
        for (int reg = 0; reg < 4; ++reg) {
            float v = acc[mt][reg] + bs;
            if (ln < 12) s_h[ln * 260 + base + reg] = v;
            psum += v;                     // lanes >= 12: weights+bias zero -> 0
        }
    }
    psum += __shfl_down(psum, 16);
    psum += __shfl_down(psum, 32);
    if (lane < 16) s_red[w][lane] = psum;
    __syncthreads();

    if (tid < 192) {
        const int co = tid >> 4, ch = tid & 15;
        const float* src = s_h + co * 260 + ch * 16;
        float4 v0 = *(const float4*)(src);
        float4 v1 = *(const float4*)(src + 4);
        float4 v2 = *(const float4*)(src + 8);
        float4 v3 = *(const float4*)(src + 12);
        const int hd = co >> 2, cl = co & 3;
        float* dst = h + ((size_t)((hd * 8 + b) * 4 + cl)) * HWSZ
                       + (size_t)(y0 + (ch >> 2)) * 512 + x1 + ((ch & 3) << 4);
        *(float4*)(dst)      = v0;
        *(float4*)(dst + 4)  = v1;
        *(float4*)(dst + 8)  = v2;
        *(float4*)(dst + 12) = v3;
    }
    if (tid < 12) {
        float t = s_red[0][tid] + s_red[1][tid] + s_red[2][tid] + s_red[3][tid];
        atomicAdd(&g2[(tid >> 2) * 32 + b * 4 + (tid & 3)], t);
    }
}

// ---------------------------------------------------------------------------
// conv1: 3 -> 32, fp32 direct, thread-per-pixel, writes packed NHWC.
// ---------------------------------------------------------------------------
__global__ __launch_bounds__(256)
void conv1_nhwc(const float* __restrict__ x, const float* __restrict__ wgt,
                const float* __restrict__ bias, const float* __restrict__ alpha,
                u32* __restrict__ out)
{
    __shared__ float s_in[3][6][72];
    __shared__ float s_w[3][9][32];
    __shared__ float s_b[32];
    const int tid = threadIdx.x;
    const int x1 = blockIdx.x * 64, y0 = blockIdx.y * 4;

    for (int i = tid; i < 3 * 6 * 66; i += 256) {
        int ci = i / 396, rm = i % 396;
        int r = rm / 66, cc = rm % 66;
        int gy = y0 - 1 + r, gx = x1 - 1 + cc;
        float v = 0.f;
        if ((unsigned)gy < 512u && (unsigned)gx < 512u)
            v = x[(size_t)ci * HWSZ + gy * 512 + gx];
        s_in[ci][r][cc] = v;
    }
    for (int i = tid; i < 864; i += 256) {
        int co = i & 31, rm = i >> 5;
        int ci = rm / 9, tap = rm % 9;
        s_w[ci][tap][co] = wgt[(co * 3 + ci) * 9 + tap];
    }
    if (tid < 32) s_b[tid] = bias[tid];
    __syncthreads();

    const int ty = tid >> 6, tx = tid & 63;
    float acc[32];
    #pragma unroll
    for (int i = 0; i < 32; ++i) acc[i] = 0.f;
    #pragma unroll
    for (int ci = 0; ci < 3; ++ci)
        #pragma unroll
        for (int tap = 0; tap < 9; ++tap) {
            const int dy = tap / 3, dx = tap % 3;
            float iv = s_in[ci][ty + dy][tx + dx];
            #pragma unroll
            for (int c4 = 0; c4 < 8; ++c4) {
                float4 wv = *(const float4*)&s_w[ci][tap][c4 * 4];
                acc[c4*4+0] = fmaf(iv, wv.x, acc[c4*4+0]);
                acc[c4*4+1] = fmaf(iv, wv.y, acc[c4*4+1]);
                acc[c4*4+2] = fmaf(iv, wv.z, acc[c4*4+2]);
                acc[c4*4+3] = fmaf(iv, wv.w, acc[c4*4+3]);
            }
        }
    const float av = alpha[0];
    u32* o = out + ((size_t)((y0 + ty) * 512 + x1 + tx)) * 32;
    #pragma unroll
    for (int c4 = 0; c4 < 8; ++c4) {
        uint4 pk;
        float t;
        t = acc[c4*4+0] + s_b[c4*4+0]; t = t > 0.f ? t : av * t; pk.x = packhl(t);
        t = acc[c4*4+1] + s_b[c4*4+1]; t = t > 0.f ? t : av * t; pk.y = packhl(t);
        t = acc[c4*4+2] + s_b[c4*4+2]; t = t > 0.f ? t : av * t; pk.z = packhl(t);
        t = acc[c4*4+3] + s_b[c4*4+3]; t = t > 0.f ? t : av * t; pk.w = packhl(t);
        *(uint4*)(o + c4 * 4) = pk;
    }
}

// ---------------------------------------------------------------------------
__global__ void zero_k(float* p, int n)
{
    int i = blockIdx.x * 256 + threadIdx.x;
    if (i < n) p[i] = 0.f;
}

__global__ void ca_kernel(const float* __restrict__ g,
                          const float* __restrict__ c11, const float* __restrict__ c12,
                          const float* __restrict__ c21, const float* __restrict__ c22,
                          const float* __restrict__ c31, const float* __restrict__ c32,
                          float* __restrict__ sOut)
{
    int t = threadIdx.x;
    if (t >= 24) return;
    int head = t / 8, b = t % 8;
    const float* c1 = head == 0 ? c11 : (head == 1 ? c21 : c31);
    const float* c2 = head == 0 ? c12 : (head == 1 ? c22 : c32);
    float m[4], v[4];
    #pragma unroll
    for (int i = 0; i < 4; ++i) m[i] = g[head * 32 + b * 4 + i] * (1.0f / 262144.0f);
    #pragma unroll
    for (int j = 0; j < 4; ++j) {
        float xv = c1[j*4+0]*m[0] + c1[j*4+1]*m[1] + c1[j*4+2]*m[2] + c1[j*4+3]*m[3];
        v[j] = fmaxf(xv, 0.f);
    }
    #pragma unroll
    for (int j = 0; j < 4; ++j) {
        float xv = c2[j*4+0]*v[0] + c2[j*4+1]*v[1] + c2[j*4+2]*v[2] + c2[j*4+3]*v[3];
        sOut[head * 32 + b * 4 + j] = 1.f / (1.f + __expf(-xv));
    }
}

// ---------------------------------------------------------------------------
// Integral image (SAT): 513x513 per (b,c) plane.
// ---------------------------------------------------------------------------
__global__ __launch_bounds__(256)
void sat_row(const float* __restrict__ src, float* __restrict__ S)
{
    const int y  = blockIdx.x;
    const int bc = blockIdx.y;
    float* Sp = S + (size_t)bc * 263169;
    const int tid = threadIdx.x;
    if (y == 0) {
        for (int i = tid; i < 513; i += 256) Sp[i] = 0.f;
        return;
    }
    const float2* row2 = (const float2*)(src + (size_t)bc * HWSZ + (size_t)(y - 1) * 512);
    float2 ab = row2[tid];
    float ps = ab.x + ab.y;
    float v = ps;
    const int lane = tid & 63;
    #pragma unroll
    for (int off = 1; off < 64; off <<= 1) {
        float u = __shfl_up(v, off);
        if (lane >= off) v += u;
    }
    __shared__ float wsum[4];
    const int wv = tid >> 6;
    if (lane == 63) wsum[wv] = v;
    __syncthreads();
    float woff = 0.f;
    #pragma unroll
    for (int k = 0; k < 4; ++k) if (k < wv) woff += wsum[k];
    float excl = woff + v - ps;
    float* o = Sp + (size_t)y * 513;
    if (tid == 0) o[0] = 0.f;
    o[1 + 2 * tid] = excl + ab.x;
    o[2 + 2 * tid] = excl + ab.x + ab.y;
}

// column scan: grid (24, 2) x 256 thr; 16-deep manual unroll keeps 16 loads
// in flight per thread (dependency is only the running sum).
__global__ __launch_bounds__(256)
void sat_col(float* __restrict__ S)
{
    const int bc = blockIdx.x;
    const int c  = 1 + blockIdx.y * 256 + threadIdx.x;   // 1..512
    float* P = S + (size_t)bc * 263169 + c;
    float run = 0.f;
    for (int r0 = 1; r0 <= 512; r0 += 16) {
        float v[16];
        #pragma unroll
        for (int i = 0; i < 16; ++i) v[i] = P[(size_t)(r0 + i) * 513];
        #pragma unroll
        for (int i = 0; i < 16; ++i) { run += v[i]; v[i] = run; }
        #pragma unroll
        for (int i = 0; i < 16; ++i) P[(size_t)(r0 + i) * 513] = v[i];
    }
}

__device__ __forceinline__ float boxsum(const float* __restrict__ S, int y, int x, int p)
{
    int y0 = max(y - p, 0), x0 = max(x - p, 0);
    int y1 = min(y + p, 511) + 1, x1 = min(x + p, 511) + 1;
    return S[y1 * 513 + x1] - S[y0 * 513 + x1] - S[y1 * 513 + x0] + S[y0 * 513 + x0];
}

// 4-pixel boxsum: same FP op order per element as scalar boxsum (bit-exact).
// Fast path (interior in x): 4 corner-row vector loads replace 16 scalars.
__device__ __forceinline__ f4 boxsum4(const float* __restrict__ S, int y, int x, int p)
{
    const int y0 = max(y - p, 0);
    const int y1 = min(y + p, 511) + 1;
    const float* R1 = S + (size_t)y1 * 513;
    const float* R0 = S + (size_t)y0 * 513;
    if (x >= p && x + p <= 508) {
        f4 a = *(const f4u*)(R1 + x + p + 1);   // (y1, x1+i)
        f4 c = *(const f4u*)(R0 + x + p + 1);   // (y0, x1+i)
        f4 b = *(const f4u*)(R1 + x - p);       // (y1, x0+i)
        f4 d = *(const f4u*)(R0 + x - p);       // (y0, x0+i)
        return a - c - b + d;                   // ((A-B)-C)+D order, as scalar
    }
    f4 r;
    #pragma unroll
    for (int i = 0; i < 4; ++i) {
        const int xi = x + i;
        const int x0 = max(xi - p, 0), x1 = min(xi + p, 511) + 1;
        r[i] = R1[x1] - R0[x1] - R1[x0] + R0[x0];
    }
    return r;
}

// fuse: 4 pixels per thread (one row segment), float4 softmax inputs and
// outputs, vectorized SAT corner loads. Grid 2048 x 256.
__global__ __launch_bounds__(256)
void fuse_kernel(const float* __restrict__ cur, const float* __restrict__ h,
                 const float* __restrict__ sv, const float* __restrict__ S,
                 float* __restrict__ out, int head)
{
    const int gid = blockIdx.x * 256 + threadIdx.x;   // 524288 threads
    const int b   = gid >> 16;                        // 65536 groups/batch
    const int pix = (gid & 65535) << 2;
    const int y   = pix >> 9;
    const int x   = pix & 511;

    const float* sp = sv + head * 32 + b * 4;
    const float* hp = h + (size_t)((head * 8 + b) * 4) * HWSZ + pix;
    f4 h0 = *(const f4*)(hp);
    f4 h1 = *(const f4*)(hp + HWSZ);
    f4 h2 = *(const f4*)(hp + 2 * HWSZ);
    f4 h3 = *(const f4*)(hp + 3 * HWSZ);
    const float s0 = sp[0], s1 = sp[1], s2 = sp[2], s3 = sp[3];

    float p0[4], p1[4], p2[4], p3[4];
    #pragma unroll
    for (int i = 0; i < 4; ++i) {
        float z0 = h0[i] * s0;
        float z1 = h1[i] * s1;
        float z2 = h2[i] * s2;
        float z3 = h3[i] * s3;
        float m  = fmaxf(fmaxf(z0, z1), fmaxf(z2, z3));
        float e0 = __expf(z0 - m), e1 = __expf(z1 - m);
        float e2 = __expf(z2 - m), e3 = __expf(z3 - m);
        float inv = 1.f / (e0 + e1 + e2 + e3);
        p0[i] = e0 * inv; p1[i] = e1 * inv; p2[i] = e2 * inv; p3[i] = e3 * inv;
    }

    #pragma unroll
    for (int c = 0; c < 3; ++c) {
        const float* Sp = S + (size_t)(b * 3 + c) * 263169;
        const size_t base = ((size_t)b * 3 + c) * HWSZ + pix;
        f4 xv = *(const f4*)(cur + base);
        f4 m2 = boxsum4(Sp, y, x, 2);
        f4 m3 = boxsum4(Sp, y, x, 7);
        f4 m4 = boxsum4(Sp, y, x, 12);
        f4 o;
        #pragma unroll
        for (int i = 0; i < 4; ++i)
            o[i] = p0[i] * xv[i] + p1[i] * (m2[i] * (1.f / 25.f))
                 + p2[i] * (m3[i] * (1.f / 225.f))
                 + p3[i] * (m4[i] * (1.f / 625.f));
        *(f4*)(out + base) = o;
    }
}

// ---------------------------------------------------------------------------
// Workspace (dwords): t1 8,388,608 | t2 16,777,216 | hbuf 25,165,824
// | gbuf 96 | sbuf 96 | bf16 weights ~83K shorts | hb16 16  -> ~201.6 MB
// ---------------------------------------------------------------------------
extern "C" void kernel_launch(void* const* d_in, const int* in_sizes, int n_in,
                              void* d_out, int out_size, void* d_ws, size_t ws_size,
                              hipStream_t stream)
{
    (void)in_sizes; (void)n_in; (void)out_size; (void)ws_size;
    const float* x    = (const float*)d_in[0];
    const float* bw1  = (const float*)d_in[1];
    const float* bb1  = (const float*)d_in[2];
    const float* a1   = (const float*)d_in[3];
    const float* bw2  = (const float*)d_in[4];
    const float* bb2  = (const float*)d_in[5];
    const float* a2   = (const float*)d_in[6];
    const float* bw3  = (const float*)d_in[7];
    const float* bb3  = (const float*)d_in[8];
    const float* a3   = (const float*)d_in[9];
    const float* h1w  = (const float*)d_in[10];
    const float* h1b  = (const float*)d_in[11];
    const float* h1c1 = (const float*)d_in[12];
    const float* h1c2 = (const float*)d_in[13];
    const float* h2w  = (const float*)d_in[14];
    const float* h2b  = (const float*)d_in[15];
    const float* h2c1 = (const float*)d_in[16];
    const float* h2c2 = (const float*)d_in[17];
    const float* h3w  = (const float*)d_in[18];
    const float* h3b  = (const float*)d_in[19];
    const float* h3c1 = (const float*)d_in[20];
    const float* h3c2 = (const float*)d_in[21];

    float* ws   = (float*)d_ws;
    u32*   t1u  = (u32*)ws;                         //  8,388,608 dwords (NHWC hl32, 32ch)
    u32*   t2u  = t1u + 8388608;                    // 16,777,216 dwords (NHWC hl32, 64ch)
    float* hbuf = (float*)(t2u + 16777216);         // 25,165,824 fl (h NCHW fp32)
    float* gbuf = hbuf + 25165824;                  // 96
    float* sbuf = gbuf + 96;                        // 96
    unsigned short* wb = (unsigned short*)(sbuf + 96);
    unsigned short* w2h = wb;                       // 18432
    unsigned short* w2l = wb + 18432;
    unsigned short* w3h = wb + 36864;
    unsigned short* w3l = wb + 55296;
    unsigned short* whh = wb + 73728;               // 4608
    unsigned short* whl = wb + 78336;
    float* hb16 = (float*)(wb + 82944);             // 16
    float* SAT  = (float*)t2u;                      // alias (6,316,056 <= 16,777,216)
    float* ping = (float*)t1u;                      // alias (6,291,456 <=  8,388,608)

    dim3 blk(256);

    prep_weights<<<dim3(163), blk, 0, stream>>>(bw2, bw3, h1w, h2w, h3w,
                                                h1b, h2b, h3b,
                                                w2h, w2l, w3h, w3l, whh, whl, hb16);
    zero_k<<<dim3(1), dim3(128), 0, stream>>>(gbuf, 96);

    // per-batch body: x[b] -> t1 -> t2 -> t1 -> heads
    for (int b = 0; b < 8; ++b) {
        conv1_nhwc<<<dim3(8, 128), blk, 0, stream>>>(x + (size_t)b * 3 * HWSZ,
                                                     bw1, bb1, a1, t1u);
        conv_mfma<32, 64><<<dim3(8, 128), blk, 0, stream>>>(t1u, w2h, w2l, bb2, a2, t2u);
        conv_mfma<64, 32><<<dim3(8, 128), blk, 0, stream>>>(t2u, w3h, w3l, bb3, a3, t1u);
        head_mfma<<<dim3(8, 128), blk, 0, stream>>>(t1u, whh, whl, hb16, hbuf, gbuf, b);
    }

    ca_kernel<<<dim3(1), dim3(64), 0, stream>>>(gbuf, h1c1, h1c2, h2c1, h2c2,
                                                h3c1, h3c2, sbuf);

    // fuse chain: x -> ping -> ping(in place) -> d_out
    const float* cur = x;
    for (int i = 0; i < 3; ++i) {
        sat_row<<<dim3(513, 24), blk, 0, stream>>>(cur, SAT);
        sat_col<<<dim3(24, 2), blk, 0, stream>>>(SAT);
        float* nxt = (i == 2) ? (float*)d_out : ping;
        fuse_kernel<<<dim3(2048), blk, 0, stream>>>(cur, hbuf, sbuf, SAT, nxt, i);
        cur = nxt;
    }
}

// Round 7
// 1425.993 us; speedup vs baseline: 1.2245x; 1.0164x over previous
//
#include <hip/hip_runtime.h>
#include <math.h>

#define HWSZ (512*512)

typedef unsigned int u32;
typedef __attribute__((ext_vector_type(8))) short short8;
typedef __attribute__((ext_vector_type(4))) float f32x4;

__device__ __forceinline__ unsigned short f2bf(float f) {
    unsigned u = __float_as_uint(f);
    unsigned r = (u + 0x7FFFu + ((u >> 16) & 1u)) >> 16;
    return (unsigned short)r;
}
__device__ __forceinline__ float bf2f(unsigned short h) {
    return __uint_as_float((unsigned)h << 16);
}
__device__ __forceinline__ u32 packhl(float v) {
    unsigned short h = f2bf(v);
    unsigned short l = f2bf(v - bf2f(h));
    return (u32)h | ((u32)l << 16);
}

// LDS tile geometry for MFMA convs: 6 rows x 72 cols x 32 ci, hi/lo planes.
// granule (8 ci) stride GRAN=3464 shorts (6928 B == 4 banks mod 32): even bank
// spread for both staging b128 writes and fragment b128 reads.
// HISTORY (r1-r6): every internal restructure of this kernel (68-col tile,
// launch-bounds>=3, reg-staged ILP, global_load_lds dual-plane, plane-major
// chunks) regressed 7-23% (allocator pins VGPR down / serializes staging, or
// format doubles HBM traffic). r0 codegen (VGPR 88, ~62us) is the keeper.
// r7 change: batch the 8 independent per-batch chains into grid.y = 128*G
// (buffers sized for G batches) -- inner loops untouched; only the halo
// bounds check becomes batch-local (yl = y0&511).
#define GRAN  3464
#define APLANE (4 * GRAN)   // 13856 shorts per plane

// ---------------------------------------------------------------------------
// Weight prep: fp32 OIHW -> [tap][co][ci] bf16 hi/lo (Markidis split).
// conv2 (64x32), conv3 (32x64), heads packed+padded to 16 co (12 valid).
// ---------------------------------------------------------------------------
__global__ void prep_weights(const float* __restrict__ w2, const float* __restrict__ w3,
                             const float* __restrict__ hw1, const float* __restrict__ hw2,
                             const float* __restrict__ hw3,
                             const float* __restrict__ hb1, const float* __restrict__ hb2,
                             const float* __restrict__ hb3,
                             unsigned short* __restrict__ w2h, unsigned short* __restrict__ w2l,
                             unsigned short* __restrict__ w3h, unsigned short* __restrict__ w3l,
                             unsigned short* __restrict__ whh, unsigned short* __restrict__ whl,
                             float* __restrict__ hb16)
{
    int i = blockIdx.x * 256 + threadIdx.x;
    if (i < 18432) {
        int tap = i / 2048, r = i % 2048, co = r / 32, ci = r % 32;
        float v = w2[((co * 32 + ci) * 9) + tap];
        unsigned short h = f2bf(v);
        w2h[i] = h; w2l[i] = f2bf(v - bf2f(h));
    } else if (i < 36864) {
        int e = i - 18432;
        int tap = e / 2048, r = e % 2048, co = r / 64, ci = r % 64;
        float v = w3[((co * 64 + ci) * 9) + tap];
        unsigned short h = f2bf(v);
        w3h[e] = h; w3l[e] = f2bf(v - bf2f(h));
    } else if (i < 41472) {
        int e = i - 36864;
        int tap = e / 512, r = e % 512, co16 = r / 32, ci = r % 32;
        float v = 0.f;
        if (co16 < 12) {
            int hd = co16 >> 2, cl = co16 & 3;
            const float* wp = hd == 0 ? hw1 : (hd == 1 ? hw2 : hw3);
            v = wp[((cl * 32 + ci) * 9) + tap];
        }
        unsigned short h = f2bf(v);
        whh[e] = h; whl[e] = f2bf(v - bf2f(h));
    } else if (i < 41488) {
        int j = i - 41472;
        float v = 0.f;
        if (j < 12) {
            const float* bp = (j >> 2) == 0 ? hb1 : ((j >> 2) == 1 ? hb2 : hb3);
            v = bp[j & 3];
        }
        hb16[j] = v;
    }
}

// ---------------------------------------------------------------------------
// Stage 6x72(66 used)xCIN-chunk tile from packed hi/lo NHWC global into LDS.
// Wave lanes: 16 cols x 4 ci-granules -> 2 KB contiguous global per instr.
// Batched grids: y0 spans G batches of 512 rows; halo check is batch-local
// (yl), so tiles at batch seams zero-pad instead of reading the neighbor.
// ---------------------------------------------------------------------------
template<int CIN>
__device__ __forceinline__ void stage_tile(const u32* __restrict__ in,
                                           unsigned short* s_a,
                                           int w, int lane, int x1, int y0, int c0)
{
    const int c16 = lane & 15;
    const int g   = lane >> 4;
    const int yb  = y0 - (y0 & 511);           // batch base row (uniform)
    for (int it = w; it < 30; it += 4) {
        int r  = it / 5;
        int cb = it % 5;
        int col = cb * 16 + c16;
        if (col < 66) {
            int yl = (y0 & 511) - 1 + r;       // row within batch image
            int gx = x1 - 1 + col;
            u32 d0=0,d1=0,d2=0,d3=0,d4=0,d5=0,d6=0,d7=0;
            if ((unsigned)yl < 512u && (unsigned)gx < 512u) {
                const int gy = yb + yl;
                const uint4* p = (const uint4*)(in + ((size_t)(gy * 512 + gx)) * CIN + c0 + g * 8);
                uint4 A = p[0], B = p[1];
                d0=A.x; d1=A.y; d2=A.z; d3=A.w; d4=B.x; d5=B.y; d6=B.z; d7=B.w;
            }
            uint4 hi, lo;
            hi.x = (d0 & 0xffffu) | (d1 << 16);
            hi.y = (d2 & 0xffffu) | (d3 << 16);
            hi.z = (d4 & 0xffffu) | (d5 << 16);
            hi.w = (d6 & 0xffffu) | (d7 << 16);
            lo.x = (d0 >> 16) | (d1 & 0xffff0000u);
            lo.y = (d2 >> 16) | (d3 & 0xffff0000u);
            lo.z = (d4 >> 16) | (d5 & 0xffff0000u);
            lo.w = (d6 >> 16) | (d7 & 0xffff0000u);
            int e = (r * 72 + col) * 8;
            *(uint4*)(s_a + g * GRAN + e) = hi;
            *(uint4*)(s_a + APLANE + g * GRAN + e) = lo;
        }
    }
}

// ---------------------------------------------------------------------------
// 3x3 conv + bias + PReLU, NHWC hi/lo packed in/out, bf16 MFMA 3-pass.
// Tile: 4 rows x 64 cols x COUT. 4 waves x 4 m-tiles; NTW n-tiles per wave.
// ---------------------------------------------------------------------------
template<int CIN, int COUT>
__global__ __launch_bounds__(256, 2)
void conv_mfma(const u32* __restrict__ in,
               const unsigned short* __restrict__ wh,
               const unsigned short* __restrict__ wl,
               const float* __restrict__ bias,
               const float* __restrict__ alpha,
               u32* __restrict__ out)
{
    constexpr int NTW = COUT / 16;
    __shared__ __align__(16) unsigned short s_a[2 * APLANE];

    const int tid  = threadIdx.x;
    const int w    = tid >> 6;
    const int lane = tid & 63;
    const int ln   = lane & 15;
    const int quad = lane >> 4;
    const int x1   = blockIdx.x * 64;
    const int y0   = blockIdx.y * 4;

    f32x4 acc[4][NTW];
    #pragma unroll
    for (int mt = 0; mt < 4; ++mt)
        #pragma unroll
        for (int nt = 0; nt < NTW; ++nt)
            acc[mt][nt] = (f32x4){0.f, 0.f, 0.f, 0.f};

    for (int c0 = 0; c0 < CIN; c0 += 32) {
        if (c0) __syncthreads();
        stage_tile<CIN>(in, s_a, w, lane, x1, y0, c0);
        __syncthreads();

        #pragma unroll
        for (int tap = 0; tap < 9; ++tap) {
            const int dy = tap / 3, dx = tap % 3;
            short8 bh[NTW], bl[NTW];
            #pragma unroll
            for (int nt = 0; nt < NTW; ++nt) {
                size_t off = ((size_t)(tap * COUT + nt * 16 + ln)) * CIN + c0 + quad * 8;
                bh[nt] = *(const short8*)(wh + off);
                bl[nt] = *(const short8*)(wl + off);
            }
            short8 ah[4], al[4];
            #pragma unroll
            for (int mt = 0; mt < 4; ++mt) {
                const int mti = w * 4 + mt;
                const int rr  = (mti >> 2) + dy;
                const int col = ((mti & 3) << 4) + ln + dx;
                const int off = quad * GRAN + (rr * 72 + col) * 8;
                ah[mt] = *(const short8*)(s_a + off);
                al[mt] = *(const short8*)(s_a + APLANE + off);
            }
            #pragma unroll
            for (int mt = 0; mt < 4; ++mt)
                #pragma unroll
                for (int nt = 0; nt < NTW; ++nt)
                    acc[mt][nt] = __builtin_amdgcn_mfma_f32_16x16x32_bf16(ah[mt], bh[nt], acc[mt][nt], 0, 0, 0);
            #pragma unroll
            for (int mt = 0; mt < 4; ++mt)
                #pragma unroll
                for (int nt = 0; nt < NTW; ++nt)
                    acc[mt][nt] = __builtin_amdgcn_mfma_f32_16x16x32_bf16(al[mt], bh[nt], acc[mt][nt], 0, 0, 0);
            #pragma unroll
            for (int mt = 0; mt < 4; ++mt)
                #pragma unroll
                for (int nt = 0; nt < NTW; ++nt)
                    acc[mt][nt] = __builtin_amdgcn_mfma_f32_16x16x32_bf16(ah[mt], bl[nt], acc[mt][nt], 0, 0, 0);
        }
    }

    const float av = alpha[0];
    float bs[NTW];
    #pragma unroll
    for (int nt = 0; nt < NTW; ++nt) bs[nt] = bias[nt * 16 + ln];
    #pragma unroll
    for (int mt = 0; mt < 4; ++mt) {
        const int mti = w * 4 + mt;
        const int y   = y0 + (mti >> 2);
        const int xb  = x1 + ((mti & 3) << 4) + quad * 4;
        #pragma unroll
        for (int nt = 0; nt < NTW; ++nt) {
            const int co = nt * 16 + ln;
            #pragma unroll
            for (int reg = 0; reg < 4; ++reg) {
                float t = acc[mt][nt][reg] + bs[nt];
                t = t > 0.f ? t : av * t;
                out[((size_t)(y * 512 + xb + reg)) * COUT + co] = packhl(t);
            }
        }
    }
}

// ---------------------------------------------------------------------------
// Head conv: 32 -> 16 co (12 valid = 3 heads x 4), MFMA 3-pass, + GAP atomics.
// Writes h planes NCHW fp32 via LDS transpose (coalesced 64-B segments).
// b_eff = b0 + (y0>>9) supports batched grids.
// ---------------------------------------------------------------------------
__global__ __launch_bounds__(256, 2)
void head_mfma(const u32* __restrict__ in,
               const unsigned short* __restrict__ wh,
               const unsigned short* __restrict__ wl,
               const float* __restrict__ hb,
               float* __restrict__ h, float* __restrict__ g2, int b0)
{
    __shared__ __align__(16) unsigned short s_a[2 * APLANE];
    __shared__ float s_red[4][16];

    const int tid  = threadIdx.x;
    const int w    = tid >> 6;
    const int lane = tid & 63;
    const int ln   = lane & 15;
    const int quad = lane >> 4;
    const int x1   = blockIdx.x * 64;
    const int y0   = blockIdx.y * 4;
    const int b    = b0 + (y0 >> 9);
    const int yl0  = y0 & 511;

    f32x4 acc[4];
    #pragma unroll
    for (int mt = 0; mt < 4; ++mt) acc[mt] = (f32x4){0.f, 0.f, 0.f, 0.f};

    stage_tile<32>(in, s_a, w, lane, x1, y0, 0);
    __syncthreads();

    #pragma unroll
    for (int tap = 0; tap < 9; ++tap) {
        const int dy = tap / 3, dx = tap % 3;
        size_t boff = (size_t)tap * 512 + ln * 32 + quad * 8;
        short8 bh = *(const short8*)(wh + boff);
        short8 bl = *(const short8*)(wl + boff);
        short8 ah[4], al[4];
        #pragma unroll
        for (int mt = 0; mt < 4; ++mt) {
            const int mti = w * 4 + mt;
            const int rr  = (mti >> 2) + dy;
            const int col = ((mti & 3) << 4) + ln + dx;
            const int off = quad * GRAN + (rr * 72 + col) * 8;
            ah[mt] = *(const short8*)(s_a + off);
            al[mt] = *(const short8*)(s_a + APLANE + off);
        }
        #pragma unroll
        for (int mt = 0; mt < 4; ++mt)
            acc[mt] = __builtin_amdgcn_mfma_f32_16x16x32_bf16(ah[mt], bh, acc[mt], 0, 0, 0);
        #pragma unroll
        for (int mt = 0; mt < 4; ++mt)
            acc[mt] = __builtin_amdgcn_mfma_f32_16x16x32_bf16(al[mt], bh, acc[mt], 0, 0, 0);
        #pragma unroll
        for (int mt = 0; mt < 4; ++mt)
            acc[mt] = __builtin_amdgcn_mfma_f32_16x16x32_bf16(ah[mt], bl, acc[mt], 0, 0, 0);
    }

    __syncthreads();                       // s_a reads done; reuse as s_h
    float* s_h = (float*)s_a;              // [12][260]
    const float bs = hb[ln];
    float psum = 0.f;
    #pragma unroll
    for (int mt = 0; mt < 4; ++mt) {
        const int mti  = w * 4 + mt;
        const int base = (mti >> 2) * 64 + ((mti & 3) << 4) + quad * 4;
        #pragma unroll
        for (int reg = 0; reg < 4; ++reg) {
            float v = acc[mt][reg] + bs;
            if (ln < 12) s_h[ln * 260 + base + reg] = v;
            psum += v;                     // lanes >= 12: weights+bias zero -> 0
        }
    }
    psum += __shfl_down(psum, 16);
    psum += __shfl_down(psum, 32);
    if (lane < 16) s_red[w][lane] = psum;
    __syncthreads();

    if (tid < 192) {
        const int co = tid >> 4, ch = tid & 15;
        const float* src = s_h + co * 260 + ch * 16;
        float4 v0 = *(const float4*)(src);
        float4 v1 = *(const float4*)(src + 4);
        float4 v2 = *(const float4*)(src + 8);
        float4 v3 = *(const float4*)(src + 12);
        const int hd = co >> 2, cl = co & 3;
        float* dst = h + ((size_t)((hd * 8 + b) * 4 + cl)) * HWSZ
                       + (size_t)(yl0 + (ch >> 2)) * 512 + x1 + ((ch & 3) << 4);
        *(float4*)(dst)      = v0;
        *(float4*)(dst + 4)  = v1;
        *(float4*)(dst + 8)  = v2;
        *(float4*)(dst + 12) = v3;
    }
    if (tid < 12) {
        float t = s_red[0][tid] + s_red[1][tid] + s_red[2][tid] + s_red[3][tid];
        atomicAdd(&g2[(tid >> 2) * 32 + b * 4 + (tid & 3)], t);
    }
}

// ---------------------------------------------------------------------------
// conv1: 3 -> 32, fp32 direct, thread-per-pixel, writes packed NHWC.
// x is the multi-batch NCHW input base for the group; b = y0>>9.
// ---------------------------------------------------------------------------
__global__ __launch_bounds__(256)
void conv1_nhwc(const float* __restrict__ x, const float* __restrict__ wgt,
                const float* __restrict__ bias, const float* __restrict__ alpha,
                u32* __restrict__ out)
{
    __shared__ float s_in[3][6][72];
    __shared__ float s_w[3][9][32];
    __shared__ float s_b[32];
    const int tid = threadIdx.x;
    const int x1 = blockIdx.x * 64, y0 = blockIdx.y * 4;
    const int b = y0 >> 9, yb0 = y0 & 511;

    for (int i = tid; i < 3 * 6 * 66; i += 256) {
        int ci = i / 396, rm = i % 396;
        int r = rm / 66, cc = rm % 66;
        int yl = yb0 - 1 + r, gx = x1 - 1 + cc;
        float v = 0.f;
        if ((unsigned)yl < 512u && (unsigned)gx < 512u)
            v = x[((size_t)(b * 3 + ci)) * HWSZ + yl * 512 + gx];
        s_in[ci][r][cc] = v;
    }
    for (int i = tid; i < 864; i += 256) {
        int co = i & 31, rm = i >> 5;
        int ci = rm / 9, tap = rm % 9;
        s_w[ci][tap][co] = wgt[(co * 3 + ci) * 9 + tap];
    }
    if (tid < 32) s_b[tid] = bias[tid];
    __syncthreads();

    const int ty = tid >> 6, tx = tid & 63;
    float acc[32];
    #pragma unroll
    for (int i = 0; i < 32; ++i) acc[i] = 0.f;
    #pragma unroll
    for (int ci = 0; ci < 3; ++ci)
        #pragma unroll
        for (int tap = 0; tap < 9; ++tap) {
            const int dy = tap / 3, dx = tap % 3;
            float iv = s_in[ci][ty + dy][tx + dx];
            #pragma unroll
            for (int c4 = 0; c4 < 8; ++c4) {
                float4 wv = *(const float4*)&s_w[ci][tap][c4 * 4];
                acc[c4*4+0] = fmaf(iv, wv.x, acc[c4*4+0]);
                acc[c4*4+1] = fmaf(iv, wv.y, acc[c4*4+1]);
                acc[c4*4+2] = fmaf(iv, wv.z, acc[c4*4+2]);
                acc[c4*4+3] = fmaf(iv, wv.w, acc[c4*4+3]);
            }
        }
    const float av = alpha[0];
    u32* o = out + ((size_t)((y0 + ty) * 512 + x1 + tx)) * 32;
    #pragma unroll
    for (int c4 = 0; c4 < 8; ++c4) {
        uint4 pk;
        float t;
        t = acc[c4*4+0] + s_b[c4*4+0]; t = t > 0.f ? t : av * t; pk.x = packhl(t);
        t = acc[c4*4+1] + s_b[c4*4+1]; t = t > 0.f ? t : av * t; pk.y = packhl(t);
        t = acc[c4*4+2] + s_b[c4*4+2]; t = t > 0.f ? t : av * t; pk.z = packhl(t);
        t = acc[c4*4+3] + s_b[c4*4+3]; t = t > 0.f ? t : av * t; pk.w = packhl(t);
        *(uint4*)(o + c4 * 4) = pk;
    }
}

// ---------------------------------------------------------------------------
__global__ void zero_k(float* p, int n)
{
    int i = blockIdx.x * 256 + threadIdx.x;
    if (i < n) p[i] = 0.f;
}

__global__ void ca_kernel(const float* __restrict__ g,
                          const float* __restrict__ c11, const float* __restrict__ c12,
                          const float* __restrict__ c21, const float* __restrict__ c22,
                          const float* __restrict__ c31, const float* __restrict__ c32,
                          float* __restrict__ sOut)
{
    int t = threadIdx.x;
    if (t >= 24) return;
    int head = t / 8, b = t % 8;
    const float* c1 = head == 0 ? c11 : (head == 1 ? c21 : c31);
    const float* c2 = head == 0 ? c12 : (head == 1 ? c22 : c32);
    float m[4], v[4];
    #pragma unroll
    for (int i = 0; i < 4; ++i) m[i] = g[head * 32 + b * 4 + i] * (1.0f / 262144.0f);
    #pragma unroll
    for (int j = 0; j < 4; ++j) {
        float xv = c1[j*4+0]*m[0] + c1[j*4+1]*m[1] + c1[j*4+2]*m[2] + c1[j*4+3]*m[3];
        v[j] = fmaxf(xv, 0.f);
    }
    #pragma unroll
    for (int j = 0; j < 4; ++j) {
        float xv = c2[j*4+0]*v[0] + c2[j*4+1]*v[1] + c2[j*4+2]*v[2] + c2[j*4+3]*v[3];
        sOut[head * 32 + b * 4 + j] = 1.f / (1.f + __expf(-xv));
    }
}

// ---------------------------------------------------------------------------
// Integral image (SAT): 513x513 per (b,c) plane.
// ---------------------------------------------------------------------------
__global__ __launch_bounds__(256)
void sat_row(const float* __restrict__ src, float* __restrict__ S)
{
    const int y  = blockIdx.x;
    const int bc = blockIdx.y;
    float* Sp = S + (size_t)bc * 263169;
    const int tid = threadIdx.x;
    if (y == 0) {
        for (int i = tid; i < 513; i += 256) Sp[i] = 0.f;
        return;
    }
    const float2* row2 = (const float2*)(src + (size_t)bc * HWSZ + (size_t)(y - 1) * 512);
    float2 ab = row2[tid];
    float ps = ab.x + ab.y;
    float v = ps;
    const int lane = tid & 63;
    #pragma unroll
    for (int off = 1; off < 64; off <<= 1) {
        float u = __shfl_up(v, off);
        if (lane >= off) v += u;
    }
    __shared__ float wsum[4];
    const int wv = tid >> 6;
    if (lane == 63) wsum[wv] = v;
    __syncthreads();
    float woff = 0.f;
    #pragma unroll
    for (int k = 0; k < 4; ++k) if (k < wv) woff += wsum[k];
    float excl = woff + v - ps;
    float* o = Sp + (size_t)y * 513;
    if (tid == 0) o[0] = 0.f;
    o[1 + 2 * tid] = excl + ab.x;
    o[2 + 2 * tid] = excl + ab.x + ab.y;
}

// column scan: grid (24, 2) x 256 thr; 16-deep manual unroll keeps 16 loads
// in flight per thread (dependency is only the running sum).
__global__ __launch_bounds__(256)
void sat_col(float* __restrict__ S)
{
    const int bc = blockIdx.x;
    const int c  = 1 + blockIdx.y * 256 + threadIdx.x;   // 1..512
    float* P = S + (size_t)bc * 263169 + c;
    float run = 0.f;
    for (int r0 = 1; r0 <= 512; r0 += 16) {
        float v[16];
        #pragma unroll
        for (int i = 0; i < 16; ++i) v[i] = P[(size_t)(r0 + i) * 513];
        #pragma unroll
        for (int i = 0; i < 16; ++i) { run += v[i]; v[i] = run; }
        #pragma unroll
        for (int i = 0; i < 16; ++i) P[(size_t)(r0 + i) * 513] = v[i];
    }
}

__device__ __forceinline__ float boxsum(const float* __restrict__ S, int y, int x, int p)
{
    int y0 = max(y - p, 0), x0 = max(x - p, 0);
    int y1 = min(y + p, 511) + 1, x1 = min(x + p, 511) + 1;
    return S[y1 * 513 + x1] - S[y0 * 513 + x1] - S[y1 * 513 + x0] + S[y0 * 513 + x0];
}

__global__ __launch_bounds__(256)
void fuse_kernel(const float* __restrict__ cur, const float* __restrict__ h,
                 const float* __restrict__ sv, const float* __restrict__ S,
                 float* __restrict__ out, int head)
{
    const int idx = blockIdx.x * 256 + threadIdx.x;
    const int b   = idx >> 18;
    const int rem = idx & 262143;
    const int y   = rem >> 9;
    const int x   = rem & 511;

    const float* sp = sv + head * 32 + b * 4;
    const float* hp = h + (size_t)((head * 8 + b) * 4) * HWSZ + rem;
    float z0 = hp[0]          * sp[0];
    float z1 = hp[HWSZ]       * sp[1];
    float z2 = hp[2 * HWSZ]   * sp[2];
    float z3 = hp[3 * HWSZ]   * sp[3];
    float m  = fmaxf(fmaxf(z0, z1), fmaxf(z2, z3));
    float e0 = __expf(z0 - m), e1 = __expf(z1 - m), e2 = __expf(z2 - m), e3 = __expf(z3 - m);
    float inv = 1.f / (e0 + e1 + e2 + e3);
    float p0 = e0 * inv, p1 = e1 * inv, p2 = e2 * inv, p3 = e3 * inv;

    #pragma unroll
    for (int c = 0; c < 3; ++c) {
        const float* Sp = S + (size_t)(b * 3 + c) * 263169;
        float xv = cur[((size_t)b * 3 + c) * HWSZ + rem];
        float m2 = boxsum(Sp, y, x, 2)  * (1.f / 25.f);
        float m3 = boxsum(Sp, y, x, 7)  * (1.f / 225.f);
        float m4 = boxsum(Sp, y, x, 12) * (1.f / 625.f);
        out[((size_t)b * 3 + c) * HWSZ + rem] = p0 * xv + p1 * m2 + p2 * m3 + p3 * m4;
    }
}

// ---------------------------------------------------------------------------
// Workspace (dwords): t1 G*8,388,608 | t2 G*16,777,216 | hbuf 25,165,824
// | gbuf 96 | sbuf 96 | bf16 weights ~83K shorts | hb16 16
// G chosen at capture time from ws_size: G=8 needs ~906MB ... G=1 ~202MB.
// ---------------------------------------------------------------------------
extern "C" void kernel_launch(void* const* d_in, const int* in_sizes, int n_in,
                              void* d_out, int out_size, void* d_ws, size_t ws_size,
                              hipStream_t stream)
{
    (void)in_sizes; (void)n_in; (void)out_size;
    const float* x    = (const float*)d_in[0];
    const float* bw1  = (const float*)d_in[1];
    const float* bb1  = (const float*)d_in[2];
    const float* a1   = (const float*)d_in[3];
    const float* bw2  = (const float*)d_in[4];
    const float* bb2  = (const float*)d_in[5];
    const float* a2   = (const float*)d_in[6];
    const float* bw3  = (const float*)d_in[7];
    const float* bb3  = (const float*)d_in[8];
    const float* a3   = (const float*)d_in[9];
    const float* h1w  = (const float*)d_in[10];
    const float* h1b  = (const float*)d_in[11];
    const float* h1c1 = (const float*)d_in[12];
    const float* h1c2 = (const float*)d_in[13];
    const float* h2w  = (const float*)d_in[14];
    const float* h2b  = (const float*)d_in[15];
    const float* h2c1 = (const float*)d_in[16];
    const float* h2c2 = (const float*)d_in[17];
    const float* h3w  = (const float*)d_in[18];
    const float* h3b  = (const float*)d_in[19];
    const float* h3c1 = (const float*)d_in[20];
    const float* h3c2 = (const float*)d_in[21];

    // pick largest batch-group size G that fits the workspace
    int G = 1;
    for (int g = 8; g > 1; g >>= 1) {
        size_t need = ((size_t)g * 25165824 + 25166016) * 4   // t1+t2+hbuf+gbuf+sbuf
                    + 82944 * 2 + 64 + 256;                   // weights + hb16 + slack
        if (ws_size >= need) { G = g; break; }
    }

    float* ws   = (float*)d_ws;
    u32*   t1u  = (u32*)ws;                          // G * 8,388,608 dwords
    u32*   t2u  = t1u + (size_t)G * 8388608;         // G * 16,777,216 dwords
    float* hbuf = (float*)(t2u + (size_t)G * 16777216);  // 25,165,824 fl
    float* gbuf = hbuf + 25165824;                   // 96
    float* sbuf = gbuf + 96;                         // 96
    unsigned short* wb = (unsigned short*)(sbuf + 96);
    unsigned short* w2h = wb;                        // 18432
    unsigned short* w2l = wb + 18432;
    unsigned short* w3h = wb + 36864;
    unsigned short* w3l = wb + 55296;
    unsigned short* whh = wb + 73728;                // 4608
    unsigned short* whl = wb + 78336;
    float* hb16 = (float*)(wb + 82944);              // 16
    float* SAT  = (float*)t2u;                       // alias (6,316,056 fl fits)
    float* ping = (float*)t1u;                       // alias (6,291,456 fl fits)

    dim3 blk(256);

    prep_weights<<<dim3(163), blk, 0, stream>>>(bw2, bw3, h1w, h2w, h3w,
                                                h1b, h2b, h3b,
                                                w2h, w2l, w3h, w3l, whh, whl, hb16);
    zero_k<<<dim3(1), dim3(128), 0, stream>>>(gbuf, 96);

    // body: groups of G batches share one launch per stage (grid.y = 128*G)
    const dim3 bodyGrid(8, 128 * G);
    for (int g = 0; g < 8; g += G) {
        conv1_nhwc<<<bodyGrid, blk, 0, stream>>>(x + (size_t)g * 3 * HWSZ,
                                                 bw1, bb1, a1, t1u);
        conv_mfma<32, 64><<<bodyGrid, blk, 0, stream>>>(t1u, w2h, w2l, bb2, a2, t2u);
        conv_mfma<64, 32><<<bodyGrid, blk, 0, stream>>>(t2u, w3h, w3l, bb3, a3, t1u);
        head_mfma<<<bodyGrid, blk, 0, stream>>>(t1u, whh, whl, hb16, hbuf, gbuf, g);
    }

    ca_kernel<<<dim3(1), dim3(64), 0, stream>>>(gbuf, h1c1, h1c2, h2c1, h2c2,
                                                h3c1, h3c2, sbuf);

    // fuse chain: x -> ping -> ping(in place) -> d_out
    const float* cur = x;
    for (int i = 0; i < 3; ++i) {
        sat_row<<<dim3(513, 24), blk, 0, stream>>>(cur, SAT);
        sat_col<<<dim3(24, 2), blk, 0, stream>>>(SAT);
        float* nxt = (i == 2) ? (float*)d_out : ping;
        fuse_kernel<<<dim3(8192), blk, 0, stream>>>(cur, hbuf, sbuf, SAT, nxt, i);
        cur = nxt;
    }
}